// Round 8
// baseline (161.721 us; speedup 1.0000x reference)
//
#include <hip/hip_runtime.h>
#include <stdint.h>

// Problem constants: B=4, N=8192, G=512, E=512, D=3E=1536
#define NP 8192
#define NG 512
#define DF 1536

using f32x4    = __attribute__((ext_vector_type(4))) float;
using bf16x8   = __attribute__((ext_vector_type(8))) __bf16;
using ushort8v = __attribute__((ext_vector_type(8))) unsigned short;

// Swizzled bf16 operand layout ("fragment order"): matrix [R rows][K cols],
// block b = (r>>4)*(K/32) + (k>>5) holds 16 rows x 32 k as 512 contiguous
// elems; offset = lane*8, lane = ((k>>3)&3)*16 + (r&15). A wave's MFMA
// fragment load is then ONE contiguous 1KB global_load_dwordx4 (or ds_read_b128).

__device__ __forceinline__ unsigned short f32_to_bf16(float f) {
  unsigned int u = __float_as_uint(f);
  u += 0x7fffu + ((u >> 16) & 1u);   // round-to-nearest-even
  return (unsigned short)(u >> 16);
}
__device__ __forceinline__ float bf2f(unsigned short u) {
  return __uint_as_float(((unsigned)u) << 16);
}

struct FusedArgs {
  const float *xyz, *centers, *H4, *H8, *H12, *w1, *w2;
  const float *g1, *be1, *m1, *v1, *g2, *be2, *m2, *v2, *b1, *b2;
  unsigned short *fswz, *w1s, *w2s, *Amatb;
  int *nidx; float *nw, *s1, *t1, *s2, *t2;
  float *outp;
};

// ============ KNN (w in [0,512)): 4 lanes/point, branchless top-3 ===========
__device__ void phase_knn(const FusedArgs& a, char* smem, int w) {
  const int tid = threadIdx.x;
  float4* cs = (float4*)smem;            // [4*129]
  const int b = w >> 7;
  for (int i = tid; i < NG; i += 256) {
    float c0 = a.centers[((size_t)b * NG + i) * 3 + 0];
    float c1 = a.centers[((size_t)b * NG + i) * 3 + 1];
    float c2 = a.centers[((size_t)b * NG + i) * 3 + 2];
    float4 v; v.x = c0; v.y = c1; v.z = c2; v.w = c0 * c0 + c1 * c1 + c2 * c2;
    cs[(i >> 7) * 129 + (i & 127)] = v;
  }
  __syncthreads();
  const int t = (w & 127) * 256 + tid;
  const int p = t >> 2, q = t & 3;
  const size_t pi = (size_t)b * NP + p;
  const float x0 = a.xyz[pi * 3 + 0], x1 = a.xyz[pi * 3 + 1], x2 = a.xyz[pi * 3 + 2];
  const float xx = x0 * x0 + x1 * x1 + x2 * x2;
  float d0 = 3.4e38f, d1 = 3.4e38f, d2 = 3.4e38f;
  int i0 = 0, i1 = 0, i2 = 0;
  const int gbase = q * 128;
  const float4* csq = cs + q * 129;
#pragma unroll 4
  for (int j = 0; j < 128; ++j) {
    float4 c = csq[j];
    float d = xx + c.w - 2.0f * (x0 * c.x + x1 * c.y + x2 * c.z);
    int g = gbase + j;
    bool c0 = d < d0, c1 = d < d1, c2 = d < d2;
    float nd2 = c1 ? d1 : (c2 ? d : d2); int ni2 = c1 ? i1 : (c2 ? g : i2);
    float nd1 = c0 ? d0 : (c1 ? d : d1); int ni1 = c0 ? i0 : (c1 ? g : i1);
    d0 = c0 ? d : d0;                    i0 = c0 ? g : i0;
    d1 = nd1; i1 = ni1; d2 = nd2; i2 = ni2;
  }
#pragma unroll
  for (int off = 1; off <= 2; off <<= 1) {
    float e0 = __shfl_xor(d0, off), e1 = __shfl_xor(d1, off), e2 = __shfl_xor(d2, off);
    int j0 = __shfl_xor(i0, off), j1 = __shfl_xor(i1, off), j2 = __shfl_xor(i2, off);
#pragma unroll
    for (int s = 0; s < 3; ++s) {
      float e = (s == 0) ? e0 : (s == 1 ? e1 : e2);
      int   j = (s == 0) ? j0 : (s == 1 ? j1 : j2);
      bool c0 = (e < d0) || (e == d0 && j < i0);
      bool c1 = (e < d1) || (e == d1 && j < i1);
      bool c2 = (e < d2) || (e == d2 && j < i2);
      float nd2 = c1 ? d1 : (c2 ? e : d2); int ni2 = c1 ? i1 : (c2 ? j : i2);
      float nd1 = c0 ? d0 : (c1 ? e : d1); int ni1 = c0 ? i0 : (c1 ? j : i1);
      d0 = c0 ? e : d0;                    i0 = c0 ? j : i0;
      d1 = nd1; i1 = ni1; d2 = nd2; i2 = ni2;
    }
  }
  if (q == 0) {
    float r0 = 1.0f / (d0 + 1e-8f), r1 = 1.0f / (d1 + 1e-8f), r2 = 1.0f / (d2 + 1e-8f);
    float inv = 1.0f / (r0 + r1 + r2);
    a.nw[pi * 3 + 0] = r0 * inv; a.nw[pi * 3 + 1] = r1 * inv; a.nw[pi * 3 + 2] = r2 * inv;
    a.nidx[pi * 3 + 0] = i0; a.nidx[pi * 3 + 1] = i1; a.nidx[pi * 3 + 2] = i2;
  }
}

// ============ cast units: u in [512,2560] ===================================
// [512,2048) fused | [2048,2432) w1 | [2432,2560) w2 | 2560 BN fold
__device__ void phase_casts(const FusedArgs& a, int u) {
  const int tid = threadIdx.x;
  if (u < 2048) {
    // ---- fused=concat(H4,H8,H12) [2048,1536] f32 -> bf16 SWIZZLED ----
    const int qd = (u - 512) * 256 + tid;
    const int L = qd & 63, t2 = qd >> 6;
    const int kc = t2 % 48, mg = t2 / 48;
    const int m = mg * 16 + (L & 15);
    const int k = kc * 32 + (L >> 4) * 8;
    const float* src = (k < 512) ? a.H4 : (k < 1024 ? a.H8 : a.H12);
    const float* sp = &src[(size_t)m * 512 + (k & 511)];
    float4 va = *(const float4*)sp, vb = *(const float4*)(sp + 4);
    ushort8v o;
    o[0] = f32_to_bf16(va.x); o[1] = f32_to_bf16(va.y);
    o[2] = f32_to_bf16(va.z); o[3] = f32_to_bf16(va.w);
    o[4] = f32_to_bf16(vb.x); o[5] = f32_to_bf16(vb.y);
    o[6] = f32_to_bf16(vb.z); o[7] = f32_to_bf16(vb.w);
    *(ushort8v*)&a.fswz[((size_t)(mg * 48 + kc)) * 512 + L * 8] = o;
  } else if (u < 2432) {
    // ---- w1 [512,1536] -> bf16 SWIZZLED ----
    const int qd = (u - 2048) * 256 + tid;
    const int L = qd & 63, t2 = qd >> 6;
    const int kc = t2 % 48, ng = t2 / 48;
    const int n = ng * 16 + (L & 15);
    const int k = kc * 32 + (L >> 4) * 8;
    const float* sp = &a.w1[(size_t)n * 1536 + k];
    float4 va = *(const float4*)sp, vb = *(const float4*)(sp + 4);
    ushort8v o;
    o[0] = f32_to_bf16(va.x); o[1] = f32_to_bf16(va.y);
    o[2] = f32_to_bf16(va.z); o[3] = f32_to_bf16(va.w);
    o[4] = f32_to_bf16(vb.x); o[5] = f32_to_bf16(vb.y);
    o[6] = f32_to_bf16(vb.z); o[7] = f32_to_bf16(vb.w);
    *(ushort8v*)&a.w1s[((size_t)(ng * 48 + kc)) * 512 + L * 8] = o;
  } else if (u < 2560) {
    // ---- w2 [512,512] -> bf16 SWIZZLED ----
    const int qd = (u - 2432) * 256 + tid;
    const int L = qd & 63, t2 = qd >> 6;
    const int kc = t2 & 15, ng = t2 >> 4;
    const int n = ng * 16 + (L & 15);
    const int k = kc * 32 + (L >> 4) * 8;
    const float* sp = &a.w2[(size_t)n * 512 + k];
    float4 va = *(const float4*)sp, vb = *(const float4*)(sp + 4);
    ushort8v o;
    o[0] = f32_to_bf16(va.x); o[1] = f32_to_bf16(va.y);
    o[2] = f32_to_bf16(va.z); o[3] = f32_to_bf16(va.w);
    o[4] = f32_to_bf16(vb.x); o[5] = f32_to_bf16(vb.y);
    o[6] = f32_to_bf16(vb.z); o[7] = f32_to_bf16(vb.w);
    *(ushort8v*)&a.w2s[((size_t)(ng * 16 + kc)) * 512 + L * 8] = o;
  } else {
    // ---- BN constant folding ----
    for (int i = tid; i < 512; i += 256) {
      float sa = a.g1[i] / sqrtf(a.v1[i] + 1e-5f);
      a.s1[i] = sa; a.t1[i] = a.be1[i] - a.m1[i] * sa;
      float sb = a.g2[i] / sqrtf(a.v2[i] + 1e-5f);
      a.s2[i] = sb; a.t2[i] = a.be2[i] - a.m2[i] * sb;
    }
  }
}

// ============ GEMM1  Amatb = bf16(s1*(fused.w1^T + b1) + t1) ================
// 256 tiles of 64x64; 4 waves, each owns a 32x32 output quadrant and runs the
// FULL K=1536 serially — no split-K, no LDS, ZERO barriers (the 5-barrier
// reduce of the 32x64 split-K version is gone). acc[2][2]=16 VGPR/wave.
// Operand traffic halves vs 32x64 tiles (98MB vs 147MB); intra-block 2x frag
// re-read is L1-served (8KB working set per kc). blk in [0,256).
__device__ void phase_gemm1(const FusedArgs& a, int blk) {
  const int tid = threadIdx.x, lane = tid & 63, wv = tid >> 6;
  const int m0 = (blk >> 3) * 64;
  const int n0 = (blk & 7) * 64;
  const int wr = wv >> 1, wc = wv & 1;          // wave's 32x32 quadrant

  const unsigned short* Ap[2];
  const unsigned short* Bp[2];
#pragma unroll
  for (int mi = 0; mi < 2; ++mi)
    Ap[mi] = a.fswz + ((size_t)((m0 >> 4) + wr * 2 + mi) * 48) * 512 + lane * 8;
#pragma unroll
  for (int ni = 0; ni < 2; ++ni)
    Bp[ni] = a.w1s  + ((size_t)((n0 >> 4) + wc * 2 + ni) * 48) * 512 + lane * 8;

  f32x4 acc[2][2];
#pragma unroll
  for (int i = 0; i < 2; ++i)
#pragma unroll
    for (int j = 0; j < 2; ++j) acc[i][j] = (f32x4){0.f, 0.f, 0.f, 0.f};

  bf16x8 af[2], bfr[2], afn[2], bfn[2];
#pragma unroll
  for (int i = 0; i < 2; ++i) {
    af[i]  = __builtin_bit_cast(bf16x8, *(const ushort8v*)(Ap[i]));
    bfr[i] = __builtin_bit_cast(bf16x8, *(const ushort8v*)(Bp[i]));
  }
#pragma unroll 1
  for (int kc = 0; kc < 48; ++kc) {
    if (kc < 47) {
#pragma unroll
      for (int i = 0; i < 2; ++i) {
        afn[i] = __builtin_bit_cast(bf16x8, *(const ushort8v*)(Ap[i] + (size_t)(kc + 1) * 512));
        bfn[i] = __builtin_bit_cast(bf16x8, *(const ushort8v*)(Bp[i] + (size_t)(kc + 1) * 512));
      }
    }
#pragma unroll
    for (int mi = 0; mi < 2; ++mi)
#pragma unroll
      for (int ni = 0; ni < 2; ++ni)
        acc[mi][ni] = __builtin_amdgcn_mfma_f32_16x16x32_bf16(af[mi], bfr[ni], acc[mi][ni], 0, 0, 0);
#pragma unroll
    for (int i = 0; i < 2; ++i) { af[i] = afn[i]; bfr[i] = bfn[i]; }
  }

  // epilogue: affine -> bf16 (relu deferred to interp), direct scalar stores.
  // C/D layout: n = lane&15, m = (lane>>4)*4 + reg  [m89-verified].
  // Amatb is L2-resident for mega; 32B-segment stores are fine at 2MB total.
#pragma unroll
  for (int mi = 0; mi < 2; ++mi) {
    const int mbase = m0 + wr * 32 + mi * 16 + (lane >> 4) * 4;
#pragma unroll
    for (int ni = 0; ni < 2; ++ni) {
      const int n = n0 + wc * 32 + ni * 16 + (lane & 15);
      const float sa = a.s1[n], ba = a.b1[n], ta = a.t1[n];
#pragma unroll
      for (int r = 0; r < 4; ++r)
        a.Amatb[(size_t)(mbase + r) * 512 + n] =
            f32_to_bf16(sa * (acc[mi][ni][r] + ba) + ta);
    }
  }
}

// ============ MEGA  interp->LDS then GEMM2 -> out ===========================
// 256 blocks x 1024 threads; block = 128 points x all 512 outputs (128KB LDS,
// 1 block/CU -> 16 waves/CU). w2s L2 re-read traffic: 512KB x 256 = 128MB.
// XCD swizzle: blockIdx&7 = xcd owns contiguous 4096-point range -> its Amatb
// batch slice (512KB) + w2s (512KB) stay L2-resident per XCD.
// Stage 1: wave wv -> rowgroup rg=wv>>1 (16 pts), kc-half (wv&1)*8; gathers
//   Amatb (L2) -> LDS in fragment order (lane*16B contiguous, conflict-free).
//   Flat 8-iter loop = 24 loads in flight (quarter-split pipeline measured
//   WORSE: 6-deep MLP + per-barrier latency re-exposure at 1 block/CU, R6).
// Stage 2: wave per 32-n slice (2 frags), 8 m-frags, acc[8][2] (64 VGPR).
// Output: PLAIN stores (nontemporal streamed 64B half-lines -> measured 2x
//   write amplification, WRITE_SIZE 130MB vs 67MB output, R6; normal stores
//   let L2 merge the two halves — R2 control showed clean 72MB).
__global__ __launch_bounds__(1024, 4) void k_mega(FusedArgs a) {
  __shared__ __align__(16) unsigned short hl[128 * 512];   // 128KB, frag order
  const int tid = threadIdx.x, lane = tid & 63, wv = tid >> 6;   // wv 0..15
  const int xcd = blockIdx.x & 7, slot = blockIdx.x >> 3;        // 32 slots/XCD
  const int m0 = (xcd * 32 + slot) * 128;

  // ---- stage 1: interp 128x512 into LDS ----
  {
    const int rg = wv >> 1, kc0 = (wv & 1) * 8;   // rg 0..7, kc0 0 or 8
    const int p = m0 + rg * 16 + (lane & 15);
    const int b = p >> 13;
    const int i0 = a.nidx[p * 3 + 0], i1 = a.nidx[p * 3 + 1], i2 = a.nidx[p * 3 + 2];
    const float w0 = a.nw[p * 3 + 0], w1v = a.nw[p * 3 + 1], w2v = a.nw[p * 3 + 2];
    const int co = kc0 * 32 + (lane >> 4) * 8;
    const unsigned short* A0 = a.Amatb + ((size_t)(b * 512 + i0)) * 512 + co;
    const unsigned short* A1 = a.Amatb + ((size_t)(b * 512 + i1)) * 512 + co;
    const unsigned short* A2 = a.Amatb + ((size_t)(b * 512 + i2)) * 512 + co;
    unsigned short* wp = hl + (size_t)(rg * 16 + kc0) * 512 + lane * 8;
#pragma unroll 4
    for (int j = 0; j < 8; ++j) {
      ushort8v u0 = *(const ushort8v*)(A0 + j * 32);
      ushort8v u1 = *(const ushort8v*)(A1 + j * 32);
      ushort8v u2 = *(const ushort8v*)(A2 + j * 32);
      ushort8v o;
#pragma unroll
      for (int jj = 0; jj < 8; ++jj) {
        float v = w0 * bf2f(u0[jj]) + w1v * bf2f(u1[jj]) + w2v * bf2f(u2[jj]);
        o[jj] = f32_to_bf16(fmaxf(v, 0.f));
      }
      *(ushort8v*)(wp + (size_t)j * 512) = o;
    }
  }
  __syncthreads();

  // ---- stage 2: out[m0..m0+127][:] = relu(s2*(hl . w2s^T + b2) + t2) ----
  const int n0 = wv * 32;
  const unsigned short* Bbase = a.w2s + (size_t)(n0 >> 4) * 16 * 512 + lane * 8;

  f32x4 acc[8][2];
#pragma unroll
  for (int i = 0; i < 8; ++i) {
    acc[i][0] = (f32x4){0.f, 0.f, 0.f, 0.f};
    acc[i][1] = (f32x4){0.f, 0.f, 0.f, 0.f};
  }

  bf16x8 bfr[2], bfn[2];
  bfr[0] = __builtin_bit_cast(bf16x8, *(const ushort8v*)(Bbase));
  bfr[1] = __builtin_bit_cast(bf16x8, *(const ushort8v*)(Bbase + (size_t)16 * 512));
#pragma unroll 1
  for (int kc = 0; kc < 16; ++kc) {
    if (kc < 15) {
      bfn[0] = __builtin_bit_cast(bf16x8,
          *(const ushort8v*)(Bbase + (size_t)(kc + 1) * 512));
      bfn[1] = __builtin_bit_cast(bf16x8,
          *(const ushort8v*)(Bbase + (size_t)(16 + kc + 1) * 512));
    }
#pragma unroll
    for (int mi = 0; mi < 8; ++mi) {
      bf16x8 af = __builtin_bit_cast(bf16x8,
          *(const ushort8v*)(hl + (size_t)(mi * 16 + kc) * 512 + lane * 8));
      acc[mi][0] = __builtin_amdgcn_mfma_f32_16x16x32_bf16(af, bfr[0], acc[mi][0], 0, 0, 0);
      acc[mi][1] = __builtin_amdgcn_mfma_f32_16x16x32_bf16(af, bfr[1], acc[mi][1], 0, 0, 0);
    }
    bfr[0] = bfn[0]; bfr[1] = bfn[1];
  }

  // C/D layout: n = lane&15, m = (lane>>4)*4 + reg.
#pragma unroll
  for (int mi = 0; mi < 8; ++mi) {
    int mbase = m0 + mi * 16 + (lane >> 4) * 4;
#pragma unroll
    for (int ni = 0; ni < 2; ++ni) {
      int n = n0 + ni * 16 + (lane & 15);
      float s = a.s2[n], bb = a.b2[n], t = a.t2[n];
      f32x4 v = acc[mi][ni];
#pragma unroll
      for (int r = 0; r < 4; ++r)
        a.outp[(size_t)(mbase + r) * 512 + n] = fmaxf(s * (v[r] + bb) + t, 0.f);
    }
  }
}

// ============ pipeline: casts -> (gemm1 || knn) -> mega =====================
__global__ __launch_bounds__(256) void k_casts(FusedArgs a) {
  phase_casts(a, 512 + blockIdx.x);
}
// 768 blocks: gemm1 64x64 [0,256) (MFMA/L2, barrier-free) || knn [256,768)
// (VALU) — disjoint pipes run concurrently on shared CUs.
__global__ __launch_bounds__(256) void k_g1knn(FusedArgs a) {
  __shared__ __align__(16) char smem[8448];
  if (blockIdx.x < 256) phase_gemm1(a, blockIdx.x);
  else                  phase_knn(a, smem, blockIdx.x - 256);
}

extern "C" void kernel_launch(void* const* d_in, const int* in_sizes, int n_in,
                              void* d_out, int out_size, void* d_ws, size_t ws_size,
                              hipStream_t stream) {
  char* ws = (char*)d_ws;
  FusedArgs a;
  a.xyz     = (const float*)d_in[0];
  a.centers = (const float*)d_in[1];
  a.H4      = (const float*)d_in[2];
  a.H8      = (const float*)d_in[3];
  a.H12     = (const float*)d_in[4];
  a.w1      = (const float*)d_in[5];
  a.b1      = (const float*)d_in[6];
  a.g1      = (const float*)d_in[7];
  a.be1     = (const float*)d_in[8];
  a.m1      = (const float*)d_in[9];
  a.v1      = (const float*)d_in[10];
  a.w2      = (const float*)d_in[11];
  a.b2      = (const float*)d_in[12];
  a.g2      = (const float*)d_in[13];
  a.be2     = (const float*)d_in[14];
  a.m2      = (const float*)d_in[15];
  a.v2      = (const float*)d_in[16];
  a.fswz  = (unsigned short*)(ws);                // 6,291,456 B
  a.w1s   = (unsigned short*)(ws + 6291456);      // 1,572,864 B
  a.w2s   = (unsigned short*)(ws + 7864320);      //   524,288 B
  a.Amatb = (unsigned short*)(ws + 8388608);      // 2,097,152 B (bf16)
  a.nidx  = (int*)           (ws + 10485760);     //   393,216 B
  a.nw    = (float*)         (ws + 10878976);     //   393,216 B
  a.s1    = (float*)         (ws + 11272192);
  a.t1 = a.s1 + 512; a.s2 = a.t1 + 512; a.t2 = a.s2 + 512;
  a.outp  = (float*)d_out;

  k_casts<<<2049, 256, 0, stream>>>(a);
  k_g1knn<<< 768, 256, 0, stream>>>(a);
  k_mega <<< 256, 1024, 0, stream>>>(a);
}

// Round 9
// 155.898 us; speedup vs baseline: 1.0374x; 1.0374x over previous
//
#include <hip/hip_runtime.h>
#include <stdint.h>

// Problem constants: B=4, N=8192, G=512, E=512, D=3E=1536
#define NP 8192
#define NG 512
#define DF 1536

using f32x4    = __attribute__((ext_vector_type(4))) float;
using bf16x8   = __attribute__((ext_vector_type(8))) __bf16;
using ushort8v = __attribute__((ext_vector_type(8))) unsigned short;

// Swizzled bf16 operand layout ("fragment order"): matrix [R rows][K cols],
// block b = (r>>4)*(K/32) + (k>>5) holds 16 rows x 32 k as 512 contiguous
// elems; offset = lane*8, lane = ((k>>3)&3)*16 + (r&15). A wave's MFMA
// fragment load is then ONE contiguous 1KB global_load_dwordx4 (or ds_read_b128).

__device__ __forceinline__ unsigned short f32_to_bf16(float f) {
  unsigned int u = __float_as_uint(f);
  u += 0x7fffu + ((u >> 16) & 1u);   // round-to-nearest-even
  return (unsigned short)(u >> 16);
}
__device__ __forceinline__ float bf2f(unsigned short u) {
  return __uint_as_float(((unsigned)u) << 16);
}

struct FusedArgs {
  const float *xyz, *centers, *H4, *H8, *H12, *w1, *w2;
  const float *g1, *be1, *m1, *v1, *g2, *be2, *m2, *v2, *b1, *b2;
  unsigned short *fswz, *w1s, *w2s, *Amatb;
  int *nidx; float *nw, *s1, *t1, *s2, *t2;
  float *outp;
};

// ============ KNN (w in [0,512)): 4 lanes/point, branchless top-3 ===========
__device__ void phase_knn(const FusedArgs& a, char* smem, int w) {
  const int tid = threadIdx.x;
  float4* cs = (float4*)smem;            // [4*129]
  const int b = w >> 7;
  for (int i = tid; i < NG; i += 256) {
    float c0 = a.centers[((size_t)b * NG + i) * 3 + 0];
    float c1 = a.centers[((size_t)b * NG + i) * 3 + 1];
    float c2 = a.centers[((size_t)b * NG + i) * 3 + 2];
    float4 v; v.x = c0; v.y = c1; v.z = c2; v.w = c0 * c0 + c1 * c1 + c2 * c2;
    cs[(i >> 7) * 129 + (i & 127)] = v;
  }
  __syncthreads();
  const int t = (w & 127) * 256 + tid;
  const int p = t >> 2, q = t & 3;
  const size_t pi = (size_t)b * NP + p;
  const float x0 = a.xyz[pi * 3 + 0], x1 = a.xyz[pi * 3 + 1], x2 = a.xyz[pi * 3 + 2];
  const float xx = x0 * x0 + x1 * x1 + x2 * x2;
  float d0 = 3.4e38f, d1 = 3.4e38f, d2 = 3.4e38f;
  int i0 = 0, i1 = 0, i2 = 0;
  const int gbase = q * 128;
  const float4* csq = cs + q * 129;
#pragma unroll 4
  for (int j = 0; j < 128; ++j) {
    float4 c = csq[j];
    float d = xx + c.w - 2.0f * (x0 * c.x + x1 * c.y + x2 * c.z);
    int g = gbase + j;
    bool c0 = d < d0, c1 = d < d1, c2 = d < d2;
    float nd2 = c1 ? d1 : (c2 ? d : d2); int ni2 = c1 ? i1 : (c2 ? g : i2);
    float nd1 = c0 ? d0 : (c1 ? d : d1); int ni1 = c0 ? i0 : (c1 ? g : i1);
    d0 = c0 ? d : d0;                    i0 = c0 ? g : i0;
    d1 = nd1; i1 = ni1; d2 = nd2; i2 = ni2;
  }
#pragma unroll
  for (int off = 1; off <= 2; off <<= 1) {
    float e0 = __shfl_xor(d0, off), e1 = __shfl_xor(d1, off), e2 = __shfl_xor(d2, off);
    int j0 = __shfl_xor(i0, off), j1 = __shfl_xor(i1, off), j2 = __shfl_xor(i2, off);
#pragma unroll
    for (int s = 0; s < 3; ++s) {
      float e = (s == 0) ? e0 : (s == 1 ? e1 : e2);
      int   j = (s == 0) ? j0 : (s == 1 ? j1 : j2);
      bool c0 = (e < d0) || (e == d0 && j < i0);
      bool c1 = (e < d1) || (e == d1 && j < i1);
      bool c2 = (e < d2) || (e == d2 && j < i2);
      float nd2 = c1 ? d1 : (c2 ? e : d2); int ni2 = c1 ? i1 : (c2 ? j : i2);
      float nd1 = c0 ? d0 : (c1 ? e : d1); int ni1 = c0 ? i0 : (c1 ? j : i1);
      d0 = c0 ? e : d0;                    i0 = c0 ? j : i0;
      d1 = nd1; i1 = ni1; d2 = nd2; i2 = ni2;
    }
  }
  if (q == 0) {
    float r0 = 1.0f / (d0 + 1e-8f), r1 = 1.0f / (d1 + 1e-8f), r2 = 1.0f / (d2 + 1e-8f);
    float inv = 1.0f / (r0 + r1 + r2);
    a.nw[pi * 3 + 0] = r0 * inv; a.nw[pi * 3 + 1] = r1 * inv; a.nw[pi * 3 + 2] = r2 * inv;
    a.nidx[pi * 3 + 0] = i0; a.nidx[pi * 3 + 1] = i1; a.nidx[pi * 3 + 2] = i2;
  }
}

// ============ cast units: u in [512,2560] ===================================
// [512,2048) fused | [2048,2432) w1 | [2432,2560) w2 | 2560 BN fold
__device__ void phase_casts(const FusedArgs& a, int u) {
  const int tid = threadIdx.x;
  if (u < 2048) {
    // ---- fused=concat(H4,H8,H12) [2048,1536] f32 -> bf16 SWIZZLED ----
    const int qd = (u - 512) * 256 + tid;
    const int L = qd & 63, t2 = qd >> 6;
    const int kc = t2 % 48, mg = t2 / 48;
    const int m = mg * 16 + (L & 15);
    const int k = kc * 32 + (L >> 4) * 8;
    const float* src = (k < 512) ? a.H4 : (k < 1024 ? a.H8 : a.H12);
    const float* sp = &src[(size_t)m * 512 + (k & 511)];
    float4 va = *(const float4*)sp, vb = *(const float4*)(sp + 4);
    ushort8v o;
    o[0] = f32_to_bf16(va.x); o[1] = f32_to_bf16(va.y);
    o[2] = f32_to_bf16(va.z); o[3] = f32_to_bf16(va.w);
    o[4] = f32_to_bf16(vb.x); o[5] = f32_to_bf16(vb.y);
    o[6] = f32_to_bf16(vb.z); o[7] = f32_to_bf16(vb.w);
    *(ushort8v*)&a.fswz[((size_t)(mg * 48 + kc)) * 512 + L * 8] = o;
  } else if (u < 2432) {
    // ---- w1 [512,1536] -> bf16 SWIZZLED ----
    const int qd = (u - 2048) * 256 + tid;
    const int L = qd & 63, t2 = qd >> 6;
    const int kc = t2 % 48, ng = t2 / 48;
    const int n = ng * 16 + (L & 15);
    const int k = kc * 32 + (L >> 4) * 8;
    const float* sp = &a.w1[(size_t)n * 1536 + k];
    float4 va = *(const float4*)sp, vb = *(const float4*)(sp + 4);
    ushort8v o;
    o[0] = f32_to_bf16(va.x); o[1] = f32_to_bf16(va.y);
    o[2] = f32_to_bf16(va.z); o[3] = f32_to_bf16(va.w);
    o[4] = f32_to_bf16(vb.x); o[5] = f32_to_bf16(vb.y);
    o[6] = f32_to_bf16(vb.z); o[7] = f32_to_bf16(vb.w);
    *(ushort8v*)&a.w1s[((size_t)(ng * 48 + kc)) * 512 + L * 8] = o;
  } else if (u < 2560) {
    // ---- w2 [512,512] -> bf16 SWIZZLED ----
    const int qd = (u - 2432) * 256 + tid;
    const int L = qd & 63, t2 = qd >> 6;
    const int kc = t2 & 15, ng = t2 >> 4;
    const int n = ng * 16 + (L & 15);
    const int k = kc * 32 + (L >> 4) * 8;
    const float* sp = &a.w2[(size_t)n * 512 + k];
    float4 va = *(const float4*)sp, vb = *(const float4*)(sp + 4);
    ushort8v o;
    o[0] = f32_to_bf16(va.x); o[1] = f32_to_bf16(va.y);
    o[2] = f32_to_bf16(va.z); o[3] = f32_to_bf16(va.w);
    o[4] = f32_to_bf16(vb.x); o[5] = f32_to_bf16(vb.y);
    o[6] = f32_to_bf16(vb.z); o[7] = f32_to_bf16(vb.w);
    *(ushort8v*)&a.w2s[((size_t)(ng * 16 + kc)) * 512 + L * 8] = o;
  } else {
    // ---- BN constant folding ----
    for (int i = tid; i < 512; i += 256) {
      float sa = a.g1[i] / sqrtf(a.v1[i] + 1e-5f);
      a.s1[i] = sa; a.t1[i] = a.be1[i] - a.m1[i] * sa;
      float sb = a.g2[i] / sqrtf(a.v2[i] + 1e-5f);
      a.s2[i] = sb; a.t2[i] = a.be2[i] - a.m2[i] * sb;
    }
  }
}

// ============ GEMM1  Amatb = bf16(s1*(fused.w1^T + b1) + t1) ================
// 512 tiles, 32x64, barrier-free wave-split-K (4 waves x K=384). blk in [0,512)
// NOTE R8: 64x64 barrier-free retile with scalar 2B epilogue stores measured
// WORSE (+4us) — the 16B ushort8v epilogue stores here and the 512-block
// gemm1/knn overlap are both load-bearing. Keep this version.
__device__ void phase_gemm1(const FusedArgs& a, char* smem, int blk) {
  float* red = (float*)smem;               // [32*65]
  const int tid = threadIdx.x, lane = tid & 63, wv = tid >> 6;
  const int m0 = (blk >> 3) * 32;
  const int n0 = (blk & 7) * 64;
  const unsigned short* Ap = a.fswz + ((size_t)(m0 >> 4) * 48 + wv * 12) * 512 + lane * 8;
  const unsigned short* Bp = a.w1s  + ((size_t)(n0 >> 4) * 48 + wv * 12) * 512 + lane * 8;

  f32x4 acc[2][4];
#pragma unroll
  for (int i = 0; i < 2; ++i)
#pragma unroll
    for (int j = 0; j < 4; ++j) acc[i][j] = (f32x4){0.f, 0.f, 0.f, 0.f};

  bf16x8 af[2], bfr[4], afn[2], bfn[4];
#pragma unroll
  for (int i = 0; i < 2; ++i)
    af[i]  = __builtin_bit_cast(bf16x8, *(const ushort8v*)(Ap + (size_t)i * 48 * 512));
#pragma unroll
  for (int i = 0; i < 4; ++i)
    bfr[i] = __builtin_bit_cast(bf16x8, *(const ushort8v*)(Bp + (size_t)i * 48 * 512));
#pragma unroll 1
  for (int kc = 0; kc < 12; ++kc) {
    if (kc < 11) {
#pragma unroll
      for (int i = 0; i < 2; ++i)
        afn[i] = __builtin_bit_cast(bf16x8, *(const ushort8v*)(Ap + (size_t)i * 48 * 512 + (kc + 1) * 512));
#pragma unroll
      for (int i = 0; i < 4; ++i)
        bfn[i] = __builtin_bit_cast(bf16x8, *(const ushort8v*)(Bp + (size_t)i * 48 * 512 + (kc + 1) * 512));
    }
#pragma unroll
    for (int mi = 0; mi < 2; ++mi)
#pragma unroll
      for (int ni = 0; ni < 4; ++ni)
        acc[mi][ni] = __builtin_amdgcn_mfma_f32_16x16x32_bf16(af[mi], bfr[ni], acc[mi][ni], 0, 0, 0);
#pragma unroll
    for (int i = 0; i < 2; ++i) af[i] = afn[i];
#pragma unroll
    for (int i = 0; i < 4; ++i) bfr[i] = bfn[i];
  }

  // 4-way cross-wave reduce through LDS
  for (int w = 0; w < 4; ++w) {
    if (wv == w) {
#pragma unroll
      for (int mi = 0; mi < 2; ++mi)
#pragma unroll
        for (int ni = 0; ni < 4; ++ni) {
          int col = ni * 16 + (lane & 15);
#pragma unroll
          for (int r = 0; r < 4; ++r) {
            int row = mi * 16 + (lane >> 4) * 4 + r;
            if (w == 0) red[row * 65 + col] = acc[mi][ni][r];
            else        red[row * 65 + col] += acc[mi][ni][r];
          }
        }
    }
    __syncthreads();
  }
  // epilogue: affine -> bf16 (relu deferred to interp), 16B stores
  const int row = tid >> 3;               // 0..31
  const int col = (tid & 7) * 8;          // 0..56
  ushort8v o;
#pragma unroll
  for (int j = 0; j < 8; ++j) {
    int n = n0 + col + j;
    float v = red[row * 65 + col + j];
    o[j] = f32_to_bf16(a.s1[n] * (v + a.b1[n]) + a.t1[n]);
  }
  *(ushort8v*)&a.Amatb[(size_t)(m0 + row) * 512 + n0 + col] = o;
}

// ============ MEGA  interp->LDS then GEMM2 -> out ===========================
// 256 blocks x 1024 threads; block = 128 points x all 512 outputs (128KB LDS,
// 1 block/CU -> 16 waves/CU). w2s L2 re-read traffic: 512KB x 256 = 128MB.
// XCD swizzle: blockIdx&7 = xcd owns contiguous 4096-point range -> its Amatb
// batch slice (512KB) + w2s (512KB) stay L2-resident per XCD.
// Stage 1: wave wv -> rowgroup rg=wv>>1 (16 pts), kc-half (wv&1)*8; gathers
//   Amatb (L2) -> LDS in fragment order (lane*16B contiguous, conflict-free).
//   Flat 8-iter loop = 24 loads in flight (quarter-split pipeline measured
//   WORSE: 6-deep MLP + per-barrier latency re-exposure at 1 block/CU, R6).
// Stage 2: wave per 32-n slice (2 frags), 8 m-frags, acc[8][2] (64 VGPR).
// Output: PLAIN stores (nontemporal streamed 64B half-lines -> measured 2x
//   write amplification, WRITE_SIZE 130MB vs 67MB output, R6; normal stores
//   let L2 merge the two halves — R2 control showed clean 72MB).
__global__ __launch_bounds__(1024, 4) void k_mega(FusedArgs a) {
  __shared__ __align__(16) unsigned short hl[128 * 512];   // 128KB, frag order
  const int tid = threadIdx.x, lane = tid & 63, wv = tid >> 6;   // wv 0..15
  const int xcd = blockIdx.x & 7, slot = blockIdx.x >> 3;        // 32 slots/XCD
  const int m0 = (xcd * 32 + slot) * 128;

  // ---- stage 1: interp 128x512 into LDS ----
  {
    const int rg = wv >> 1, kc0 = (wv & 1) * 8;   // rg 0..7, kc0 0 or 8
    const int p = m0 + rg * 16 + (lane & 15);
    const int b = p >> 13;
    const int i0 = a.nidx[p * 3 + 0], i1 = a.nidx[p * 3 + 1], i2 = a.nidx[p * 3 + 2];
    const float w0 = a.nw[p * 3 + 0], w1v = a.nw[p * 3 + 1], w2v = a.nw[p * 3 + 2];
    const int co = kc0 * 32 + (lane >> 4) * 8;
    const unsigned short* A0 = a.Amatb + ((size_t)(b * 512 + i0)) * 512 + co;
    const unsigned short* A1 = a.Amatb + ((size_t)(b * 512 + i1)) * 512 + co;
    const unsigned short* A2 = a.Amatb + ((size_t)(b * 512 + i2)) * 512 + co;
    unsigned short* wp = hl + (size_t)(rg * 16 + kc0) * 512 + lane * 8;
#pragma unroll 4
    for (int j = 0; j < 8; ++j) {
      ushort8v u0 = *(const ushort8v*)(A0 + j * 32);
      ushort8v u1 = *(const ushort8v*)(A1 + j * 32);
      ushort8v u2 = *(const ushort8v*)(A2 + j * 32);
      ushort8v o;
#pragma unroll
      for (int jj = 0; jj < 8; ++jj) {
        float v = w0 * bf2f(u0[jj]) + w1v * bf2f(u1[jj]) + w2v * bf2f(u2[jj]);
        o[jj] = f32_to_bf16(fmaxf(v, 0.f));
      }
      *(ushort8v*)(wp + (size_t)j * 512) = o;
    }
  }
  __syncthreads();

  // ---- stage 2: out[m0..m0+127][:] = relu(s2*(hl . w2s^T + b2) + t2) ----
  const int n0 = wv * 32;
  const unsigned short* Bbase = a.w2s + (size_t)(n0 >> 4) * 16 * 512 + lane * 8;

  f32x4 acc[8][2];
#pragma unroll
  for (int i = 0; i < 8; ++i) {
    acc[i][0] = (f32x4){0.f, 0.f, 0.f, 0.f};
    acc[i][1] = (f32x4){0.f, 0.f, 0.f, 0.f};
  }

  bf16x8 bfr[2], bfn[2];
  bfr[0] = __builtin_bit_cast(bf16x8, *(const ushort8v*)(Bbase));
  bfr[1] = __builtin_bit_cast(bf16x8, *(const ushort8v*)(Bbase + (size_t)16 * 512));
#pragma unroll 1
  for (int kc = 0; kc < 16; ++kc) {
    if (kc < 15) {
      bfn[0] = __builtin_bit_cast(bf16x8,
          *(const ushort8v*)(Bbase + (size_t)(kc + 1) * 512));
      bfn[1] = __builtin_bit_cast(bf16x8,
          *(const ushort8v*)(Bbase + (size_t)(16 + kc + 1) * 512));
    }
#pragma unroll
    for (int mi = 0; mi < 8; ++mi) {
      bf16x8 af = __builtin_bit_cast(bf16x8,
          *(const ushort8v*)(hl + (size_t)(mi * 16 + kc) * 512 + lane * 8));
      acc[mi][0] = __builtin_amdgcn_mfma_f32_16x16x32_bf16(af, bfr[0], acc[mi][0], 0, 0, 0);
      acc[mi][1] = __builtin_amdgcn_mfma_f32_16x16x32_bf16(af, bfr[1], acc[mi][1], 0, 0, 0);
    }
    bfr[0] = bfn[0]; bfr[1] = bfn[1];
  }

  // C/D layout: n = lane&15, m = (lane>>4)*4 + reg.
#pragma unroll
  for (int mi = 0; mi < 8; ++mi) {
    int mbase = m0 + mi * 16 + (lane >> 4) * 4;
#pragma unroll
    for (int ni = 0; ni < 2; ++ni) {
      int n = n0 + ni * 16 + (lane & 15);
      float s = a.s2[n], bb = a.b2[n], t = a.t2[n];
      f32x4 v = acc[mi][ni];
#pragma unroll
      for (int r = 0; r < 4; ++r)
        a.outp[(size_t)(mbase + r) * 512 + n] = fmaxf(s * (v[r] + bb) + t, 0.f);
    }
  }
}

// ============ pipeline: casts -> (gemm1 || knn) -> mega =====================
__global__ __launch_bounds__(256) void k_casts(FusedArgs a) {
  phase_casts(a, 512 + blockIdx.x);
}
__global__ __launch_bounds__(256) void k_g1knn(FusedArgs a) {
  __shared__ __align__(16) char smem[8448];
  if (blockIdx.x < 512) phase_gemm1(a, smem, blockIdx.x);
  else                  phase_knn(a, smem, blockIdx.x - 512);
}

extern "C" void kernel_launch(void* const* d_in, const int* in_sizes, int n_in,
                              void* d_out, int out_size, void* d_ws, size_t ws_size,
                              hipStream_t stream) {
  char* ws = (char*)d_ws;
  FusedArgs a;
  a.xyz     = (const float*)d_in[0];
  a.centers = (const float*)d_in[1];
  a.H4      = (const float*)d_in[2];
  a.H8      = (const float*)d_in[3];
  a.H12     = (const float*)d_in[4];
  a.w1      = (const float*)d_in[5];
  a.b1      = (const float*)d_in[6];
  a.g1      = (const float*)d_in[7];
  a.be1     = (const float*)d_in[8];
  a.m1      = (const float*)d_in[9];
  a.v1      = (const float*)d_in[10];
  a.w2      = (const float*)d_in[11];
  a.b2      = (const float*)d_in[12];
  a.g2      = (const float*)d_in[13];
  a.be2     = (const float*)d_in[14];
  a.m2      = (const float*)d_in[15];
  a.v2      = (const float*)d_in[16];
  a.fswz  = (unsigned short*)(ws);                // 6,291,456 B
  a.w1s   = (unsigned short*)(ws + 6291456);      // 1,572,864 B
  a.w2s   = (unsigned short*)(ws + 7864320);      //   524,288 B
  a.Amatb = (unsigned short*)(ws + 8388608);      // 2,097,152 B (bf16)
  a.nidx  = (int*)           (ws + 10485760);     //   393,216 B
  a.nw    = (float*)         (ws + 10878976);     //   393,216 B
  a.s1    = (float*)         (ws + 11272192);
  a.t1 = a.s1 + 512; a.s2 = a.t1 + 512; a.t2 = a.s2 + 512;
  a.outp  = (float*)d_out;

  k_casts<<<2049, 256, 0, stream>>>(a);
  k_g1knn<<<1024, 256, 0, stream>>>(a);
  k_mega <<< 256, 1024, 0, stream>>>(a);
}